// Round 1
// baseline (752.253 us; speedup 1.0000x reference)
//
#include <hip/hip_runtime.h>
#include <hip/hip_bf16.h>

#define N_NODES 50000
#define N_EDGES 800000
#define D_IN 64
#define D_EDGE 32
#define D_HID 128

using u32 = unsigned int;

// ---- bf16 helpers via bit ops (RNE), no API dependence ----
__device__ __forceinline__ u32 f2bf(float f) {
    u32 b = __float_as_uint(f);
    return (b + 0x7FFFu + ((b >> 16) & 1u)) >> 16;
}
__device__ __forceinline__ u32 pk_bf16(float lo, float hi) {
    return f2bf(lo) | (f2bf(hi) << 16);
}
__device__ __forceinline__ float bf2f(u32 us) {  // us: low 16 bits hold bf16
    return __uint_as_float(us << 16);
}

__device__ __forceinline__ float fast_tanh(float p) {
    // 1 - 2/(e^{2p}+1); exp(+inf)->inf gives 1-0=1, exp(-big)->0 gives -1. NaN-free.
    return 1.f - 2.f / (__expf(2.f * p) + 1.f);
}

// ============ Kernel 1: per-edge MLP + gather-multiply + score ============
__global__ __launch_bounds__(256) void edge_kernel(
    const float* __restrict__ x, const int* __restrict__ src_idx,
    const float* __restrict__ ea,
    const float* __restrict__ W1, const float* __restrict__ b1,
    const float* __restrict__ W2, const float* __restrict__ b2,
    const float* __restrict__ av,
    u32* __restrict__ msg /* [E][32] u32 = 64 bf16 */,
    float* __restrict__ scores)
{
    int e = blockIdx.x * 256 + threadIdx.x;
    if (e >= N_EDGES) return;

    // load edge_attr row (32 floats, contiguous 128B per thread)
    float a[D_EDGE];
    const float4* ea4 = reinterpret_cast<const float4*>(ea) + (size_t)e * 8;
#pragma unroll
    for (int q = 0; q < 8; ++q) {
        float4 v = ea4[q];
        a[4*q+0] = v.x; a[4*q+1] = v.y; a[4*q+2] = v.z; a[4*q+3] = v.w;
    }

    float ew[64];
#pragma unroll
    for (int j = 0; j < 64; ++j) ew[j] = b2[j];   // uniform -> s_load

    // process hidden dim in 4 chunks of 32 to bound register pressure
#pragma unroll
    for (int c = 0; c < 4; ++c) {
        float h[32];
#pragma unroll
        for (int j = 0; j < 32; ++j) h[j] = b1[c*32 + j];
#pragma unroll 4
        for (int i = 0; i < D_EDGE; ++i) {
            float ai = a[i];
            const float* w = W1 + i * D_HID + c * 32;  // uniform -> s_load
#pragma unroll
            for (int j = 0; j < 32; ++j) h[j] = fmaf(ai, w[j], h[j]);
        }
#pragma unroll
        for (int j = 0; j < 32; ++j) h[j] = fast_tanh(h[j]);
#pragma unroll 4
        for (int i = 0; i < 32; ++i) {
            float hi = h[i];
            const float* w = W2 + (c*32 + i) * D_IN;   // uniform -> s_load
#pragma unroll
            for (int j = 0; j < 64; ++j) ew[j] = fmaf(hi, w[j], ew[j]);
        }
    }

    int s = src_idx[e];
    const float4* xr = reinterpret_cast<const float4*>(x) + (size_t)s * 16;
    u32* mrow = msg + (size_t)e * 32;
    float sc = 0.f;
#pragma unroll
    for (int q = 0; q < 8; ++q) {
        float4 v0 = xr[2*q], v1 = xr[2*q+1];
        float m0 = v0.x * ew[8*q+0], m1 = v0.y * ew[8*q+1];
        float m2 = v0.z * ew[8*q+2], m3 = v0.w * ew[8*q+3];
        float m4 = v1.x * ew[8*q+4], m5 = v1.y * ew[8*q+5];
        float m6 = v1.z * ew[8*q+6], m7 = v1.w * ew[8*q+7];
        sc = fmaf(m0, av[8*q+0], sc); sc = fmaf(m1, av[8*q+1], sc);
        sc = fmaf(m2, av[8*q+2], sc); sc = fmaf(m3, av[8*q+3], sc);
        sc = fmaf(m4, av[8*q+4], sc); sc = fmaf(m5, av[8*q+5], sc);
        sc = fmaf(m6, av[8*q+6], sc); sc = fmaf(m7, av[8*q+7], sc);
        uint4 p;
        p.x = pk_bf16(m0, m1); p.y = pk_bf16(m2, m3);
        p.z = pk_bf16(m4, m5); p.w = pk_bf16(m6, m7);
        reinterpret_cast<uint4*>(mrow)[q] = p;
    }
    scores[e] = sc;
}

// ============ Sorting: zero / histogram / scan / scatter ============
__global__ void zero_kernel(int* __restrict__ p, int n) {
    int i = blockIdx.x * 256 + threadIdx.x;
    if (i < n) p[i] = 0;
}

__global__ void hist_kernel(const int* __restrict__ tgt, int* __restrict__ cnt) {
    int e = blockIdx.x * 256 + threadIdx.x;
    if (e < N_EDGES) atomicAdd(&cnt[tgt[e]], 1);
}

__global__ __launch_bounds__(1024) void scan_kernel(const int* __restrict__ cnt,
                                                    int* __restrict__ offs) {
    __shared__ int wsum[16];
    __shared__ int carry_s;
    int tid = threadIdx.x, lane = tid & 63, wid = tid >> 6;
    if (tid == 0) { carry_s = 0; offs[0] = 0; }
    __syncthreads();
    for (int base = 0; base < N_NODES; base += 1024) {
        int i = base + tid;
        int v = (i < N_NODES) ? cnt[i] : 0;
        int incl = v;
#pragma unroll
        for (int off = 1; off < 64; off <<= 1) {
            int t = __shfl_up(incl, off);
            if (lane >= off) incl += t;
        }
        if (lane == 63) wsum[wid] = incl;
        __syncthreads();
        if (tid < 16) {
            int sv = wsum[tid];
#pragma unroll
            for (int off = 1; off < 16; off <<= 1) {
                int t = __shfl_up(sv, off);
                if (tid >= off) sv += t;
            }
            wsum[tid] = sv;
        }
        __syncthreads();
        int carry = carry_s;
        int tot = wsum[15];
        int excl_wave = (wid > 0) ? wsum[wid - 1] : 0;
        if (i < N_NODES) offs[i + 1] = carry + excl_wave + incl;
        __syncthreads();
        if (tid == 0) carry_s = carry + tot;
        __syncthreads();
    }
}

__global__ void scatter_kernel(const int* __restrict__ tgt, const int* __restrict__ offs,
                               int* __restrict__ cursor, int* __restrict__ sorted) {
    int e = blockIdx.x * 256 + threadIdx.x;
    if (e >= N_EDGES) return;
    int t = tgt[e];
    int p = offs[t] + atomicAdd(&cursor[t], 1);
    sorted[p] = e;
}

// ============ Kernel 3: per-node softmax + weighted aggregation ============
__global__ __launch_bounds__(256) void agg_kernel(
    const int* __restrict__ offs, const int* __restrict__ sorted,
    const float* __restrict__ scores, const unsigned short* __restrict__ msgb,
    float* __restrict__ out, float* __restrict__ aw_out)
{
    int node = blockIdx.x * 4 + (threadIdx.x >> 6);
    int lane = threadIdx.x & 63;
    if (node >= N_NODES) return;
    int beg = offs[node], end = offs[node + 1];

    float mx = -1e30f;
    for (int k = beg + lane; k < end; k += 64) mx = fmaxf(mx, scores[sorted[k]]);
#pragma unroll
    for (int off = 32; off; off >>= 1) mx = fmaxf(mx, __shfl_xor(mx, off));

    float den = 0.f;
    for (int k = beg + lane; k < end; k += 64) den += __expf(scores[sorted[k]] - mx);
#pragma unroll
    for (int off = 32; off; off >>= 1) den += __shfl_xor(den, off);

    float acc = 0.f;
    for (int k = beg; k < end; ++k) {
        int e = sorted[k];                       // uniform per iteration
        float aw = __expf(scores[e] - mx) / den;
        float m = bf2f((u32)msgb[(size_t)e * 64 + lane]);
        acc = fmaf(m, aw, acc);
        if (lane == 0) aw_out[e] = aw;
    }
    out[(size_t)node * 64 + lane] = acc;
}

// ============ launch ============
extern "C" void kernel_launch(void* const* d_in, const int* in_sizes, int n_in,
                              void* d_out, int out_size, void* d_ws, size_t ws_size,
                              hipStream_t stream)
{
    const float* x  = (const float*)d_in[0];
    const int*   ei = (const int*)d_in[1];
    const float* ea = (const float*)d_in[2];
    const float* W1 = (const float*)d_in[3];
    const float* b1 = (const float*)d_in[4];
    const float* W2 = (const float*)d_in[5];
    const float* b2 = (const float*)d_in[6];
    const float* av = (const float*)d_in[7];
    const int* src = ei;
    const int* tgt = ei + N_EDGES;

    char* ws = (char*)d_ws;
    size_t off = 0;
    u32* msg      = (u32*)(ws + off);   off += (size_t)N_EDGES * 64 * 2;   // bf16 messages
    float* scores = (float*)(ws + off); off += (size_t)N_EDGES * 4;
    int* sorted   = (int*)(ws + off);   off += (size_t)N_EDGES * 4;
    int* cnt      = (int*)(ws + off);   off += (size_t)N_NODES * 4;
    int* cursor   = (int*)(ws + off);   off += (size_t)N_NODES * 4;
    int* offs     = (int*)(ws + off);   off += (size_t)(N_NODES + 1) * 4;

    float* out    = (float*)d_out;
    float* aw_out = out + (size_t)N_NODES * 64;

    // zero cnt+cursor (contiguous)
    zero_kernel<<<(2 * N_NODES + 255) / 256, 256, 0, stream>>>(cnt, 2 * N_NODES);
    hist_kernel<<<(N_EDGES + 255) / 256, 256, 0, stream>>>(tgt, cnt);
    scan_kernel<<<1, 1024, 0, stream>>>(cnt, offs);
    scatter_kernel<<<(N_EDGES + 255) / 256, 256, 0, stream>>>(tgt, offs, cursor, sorted);
    edge_kernel<<<(N_EDGES + 255) / 256, 256, 0, stream>>>(x, src, ea, W1, b1, W2, b2, av,
                                                           msg, scores);
    agg_kernel<<<(N_NODES + 3) / 4, 256, 0, stream>>>(offs, sorted, scores,
                                                      (const unsigned short*)msg, out, aw_out);
}

// Round 2
// 352.961 us; speedup vs baseline: 2.1313x; 2.1313x over previous
//
#include <hip/hip_runtime.h>
#include <hip/hip_bf16.h>

#define N_NODES 50000
#define N_EDGES 800000
#define D_IN 64
#define D_EDGE 32
#define D_HID 128

using u32 = unsigned int;
typedef short bf16x8 __attribute__((ext_vector_type(8)));
typedef float f32x4 __attribute__((ext_vector_type(4)));

// ---- bf16 helpers via bit ops (RNE) ----
__device__ __forceinline__ u32 f2bf(float f) {
    u32 b = __float_as_uint(f);
    return (b + 0x7FFFu + ((b >> 16) & 1u)) >> 16;
}
__device__ __forceinline__ float bf2f(u32 us) {
    return __uint_as_float(us << 16);
}
__device__ __forceinline__ float fast_tanh(float p) {
    return 1.f - 2.f / (__expf(2.f * p) + 1.f);
}

// ============ Kernel 1: MFMA edge MLP + gather-multiply + score ============
// Per wave: 16 edges. GEMM1: [16,32]@[32,128] (1 k-step x 8 n-tiles).
// tanh -> LDS transpose (XOR-swizzled) -> GEMM2: [16,128]@[128,64] (4x4).
#define EDGE_BLOCKS 1024
#define TILES_TOTAL (N_EDGES / 16)

__global__ __launch_bounds__(256, 2) void edge_mfma_kernel(
    const float* __restrict__ x, const int* __restrict__ src_idx,
    const float* __restrict__ ea,
    const float* __restrict__ W1, const float* __restrict__ b1,
    const float* __restrict__ W2, const float* __restrict__ b2,
    const float* __restrict__ av,
    unsigned short* __restrict__ msg /* [E][64] bf16 */,
    float* __restrict__ scores)
{
    __shared__ unsigned short hbuf[4][16 * 128];   // 4KB per wave, 16KB total
    const int wid = threadIdx.x >> 6, lane = threadIdx.x & 63;
    const int q = lane >> 4, c = lane & 15;

    // ---- hoist weights into registers (once per block) ----
    // k-slot bijection: k = q*8 + j, applied identically to A and B frags.
    bf16x8 w1f[8];
#pragma unroll
    for (int t = 0; t < 8; ++t)
#pragma unroll
        for (int j = 0; j < 8; ++j)
            w1f[t][j] = (short)f2bf(W1[(q * 8 + j) * D_HID + t * 16 + c]);
    bf16x8 w2f[4][4];
#pragma unroll
    for (int s = 0; s < 4; ++s)
#pragma unroll
        for (int t2 = 0; t2 < 4; ++t2)
#pragma unroll
            for (int j = 0; j < 8; ++j)
                w2f[s][t2][j] = (short)f2bf(W2[(s * 32 + q * 8 + j) * D_IN + t2 * 16 + c]);
    float b1v[8], b2v[4], avv[4];
#pragma unroll
    for (int t = 0; t < 8; ++t) b1v[t] = b1[t * 16 + c];
#pragma unroll
    for (int t2 = 0; t2 < 4; ++t2) { b2v[t2] = b2[t2 * 16 + c]; avv[t2] = av[t2 * 16 + c]; }

    char* hb = (char*)hbuf[wid];
    const int nwaves = gridDim.x * 4;

    for (int T = blockIdx.x * 4 + wid; T < TILES_TOTAL; T += nwaves) {
        const int eb = T * 16;

        // ---- A1 frag: edge_attr rows, lane holds row c, k = q*8+j ----
        const float* ar = ea + (size_t)(eb + c) * D_EDGE + q * 8;
        float4 va = *(const float4*)ar;
        float4 vb = *(const float4*)(ar + 4);
        bf16x8 a1;
        a1[0] = (short)f2bf(va.x); a1[1] = (short)f2bf(va.y);
        a1[2] = (short)f2bf(va.z); a1[3] = (short)f2bf(va.w);
        a1[4] = (short)f2bf(vb.x); a1[5] = (short)f2bf(vb.y);
        a1[6] = (short)f2bf(vb.z); a1[7] = (short)f2bf(vb.w);

        // ---- GEMM1 (bias folded into C: depends only on col) ----
        f32x4 acc[8];
#pragma unroll
        for (int t = 0; t < 8; ++t) {
            f32x4 ci = {b1v[t], b1v[t], b1v[t], b1v[t]};
            acc[t] = __builtin_amdgcn_mfma_f32_16x16x32_bf16(a1, w1f[t], ci, 0, 0, 0);
        }

        // ---- tanh + pack + swizzled LDS write ----
        // C/D layout (m89): value at row=(q*4+r), col=(t*16+c)
#pragma unroll
        for (int t = 0; t < 8; ++t)
#pragma unroll
            for (int r = 0; r < 4; ++r) {
                int er = q * 4 + r;
                float hv = fast_tanh(acc[t][r]);
                int byte_off = (er * 256 + (t * 16 + c) * 2) ^ ((er & 7) << 4);
                *(unsigned short*)(hb + byte_off) = (unsigned short)f2bf(hv);
            }

        // ---- A2 frags from LDS (b128, swizzled read; same-wave dep) ----
        bf16x8 a2[4];
#pragma unroll
        for (int s = 0; s < 4; ++s) {
            int byte_off = (c * 256 + s * 64 + q * 16) ^ ((c & 7) << 4);
            a2[s] = *(bf16x8*)(hb + byte_off);
        }

        // ---- GEMM2 ----
        f32x4 acc2[4];
#pragma unroll
        for (int t2 = 0; t2 < 4; ++t2) {
            f32x4 ci = {b2v[t2], b2v[t2], b2v[t2], b2v[t2]};
            acc2[t2] = ci;
        }
#pragma unroll
        for (int s = 0; s < 4; ++s)
#pragma unroll
            for (int t2 = 0; t2 < 4; ++t2)
                acc2[t2] = __builtin_amdgcn_mfma_f32_16x16x32_bf16(a2[s], w2f[s][t2], acc2[t2], 0, 0, 0);

        // ---- epilogue: gather x, msg = x*ew (bf16 store), score partials ----
        float p[4];
#pragma unroll
        for (int r = 0; r < 4; ++r) {
            int e = eb + q * 4 + r;
            int sidx = src_idx[e];
            const float* xr = x + (size_t)sidx * D_IN;
            float pr = 0.f;
#pragma unroll
            for (int t2 = 0; t2 < 4; ++t2) {
                float m = xr[t2 * 16 + c] * acc2[t2][r];
                pr = fmaf(m, avv[t2], pr);
                msg[(size_t)e * D_IN + t2 * 16 + c] = (unsigned short)f2bf(m);
            }
            p[r] = pr;
        }
        // reduce each p[r] over the 16 lanes of this q-group
#pragma unroll
        for (int r = 0; r < 4; ++r) {
#pragma unroll
            for (int mskw = 1; mskw < 16; mskw <<= 1)
                p[r] += __shfl_xor(p[r], mskw, 16);
        }
        if (c == 0) {
#pragma unroll
            for (int r = 0; r < 4; ++r) scores[eb + q * 4 + r] = p[r];
        }
    }
}

// ============ Sorting: zero / histogram / scan / scatter ============
__global__ void zero_kernel(int* __restrict__ p, int n) {
    int i = blockIdx.x * 256 + threadIdx.x;
    if (i < n) p[i] = 0;
}

__global__ void hist_kernel(const int* __restrict__ tgt, int* __restrict__ cnt) {
    int e = blockIdx.x * 256 + threadIdx.x;
    if (e < N_EDGES) atomicAdd(&cnt[tgt[e]], 1);
}

__global__ __launch_bounds__(1024) void scan_kernel(const int* __restrict__ cnt,
                                                    int* __restrict__ offs) {
    __shared__ int wsum[16];
    __shared__ int carry_s;
    int tid = threadIdx.x, lane = tid & 63, wid = tid >> 6;
    if (tid == 0) { carry_s = 0; offs[0] = 0; }
    __syncthreads();
    for (int base = 0; base < N_NODES; base += 1024) {
        int i = base + tid;
        int v = (i < N_NODES) ? cnt[i] : 0;
        int incl = v;
#pragma unroll
        for (int off = 1; off < 64; off <<= 1) {
            int t = __shfl_up(incl, off);
            if (lane >= off) incl += t;
        }
        if (lane == 63) wsum[wid] = incl;
        __syncthreads();
        if (tid < 16) {
            int sv = wsum[tid];
#pragma unroll
            for (int off = 1; off < 16; off <<= 1) {
                int t = __shfl_up(sv, off);
                if (tid >= off) sv += t;
            }
            wsum[tid] = sv;
        }
        __syncthreads();
        int carry = carry_s;
        int tot = wsum[15];
        int excl_wave = (wid > 0) ? wsum[wid - 1] : 0;
        if (i < N_NODES) offs[i + 1] = carry + excl_wave + incl;
        __syncthreads();
        if (tid == 0) carry_s = carry + tot;
        __syncthreads();
    }
}

__global__ void scatter_kernel(const int* __restrict__ tgt, const int* __restrict__ offs,
                               int* __restrict__ cursor, int* __restrict__ sorted) {
    int e = blockIdx.x * 256 + threadIdx.x;
    if (e >= N_EDGES) return;
    int t = tgt[e];
    int p = offs[t] + atomicAdd(&cursor[t], 1);
    sorted[p] = e;
}

// ============ Kernel 3: per-node softmax + weighted aggregation ============
__global__ __launch_bounds__(256) void agg_kernel(
    const int* __restrict__ offs, const int* __restrict__ sorted,
    const float* __restrict__ scores, const unsigned short* __restrict__ msgb,
    float* __restrict__ out, float* __restrict__ aw_out)
{
    int node = blockIdx.x * 4 + (threadIdx.x >> 6);
    int lane = threadIdx.x & 63;
    if (node >= N_NODES) return;
    int beg = offs[node], end = offs[node + 1];

    float mx = -1e30f;
    for (int k = beg + lane; k < end; k += 64) mx = fmaxf(mx, scores[sorted[k]]);
#pragma unroll
    for (int off = 32; off; off >>= 1) mx = fmaxf(mx, __shfl_xor(mx, off));

    float den = 0.f;
    for (int k = beg + lane; k < end; k += 64) den += __expf(scores[sorted[k]] - mx);
#pragma unroll
    for (int off = 32; off; off >>= 1) den += __shfl_xor(den, off);

    float acc = 0.f;
    for (int k = beg; k < end; ++k) {
        int e = sorted[k];
        float aw = __expf(scores[e] - mx) / den;
        float m = bf2f((u32)msgb[(size_t)e * 64 + lane]);
        acc = fmaf(m, aw, acc);
        if (lane == 0) aw_out[e] = aw;
    }
    out[(size_t)node * 64 + lane] = acc;
}

// ============ launch ============
extern "C" void kernel_launch(void* const* d_in, const int* in_sizes, int n_in,
                              void* d_out, int out_size, void* d_ws, size_t ws_size,
                              hipStream_t stream)
{
    const float* x  = (const float*)d_in[0];
    const int*   ei = (const int*)d_in[1];
    const float* ea = (const float*)d_in[2];
    const float* W1 = (const float*)d_in[3];
    const float* b1 = (const float*)d_in[4];
    const float* W2 = (const float*)d_in[5];
    const float* b2 = (const float*)d_in[6];
    const float* av = (const float*)d_in[7];
    const int* src = ei;
    const int* tgt = ei + N_EDGES;

    char* ws = (char*)d_ws;
    size_t off = 0;
    unsigned short* msg = (unsigned short*)(ws + off); off += (size_t)N_EDGES * 64 * 2;
    float* scores = (float*)(ws + off); off += (size_t)N_EDGES * 4;
    int* sorted   = (int*)(ws + off);   off += (size_t)N_EDGES * 4;
    int* cnt      = (int*)(ws + off);   off += (size_t)N_NODES * 4;
    int* cursor   = (int*)(ws + off);   off += (size_t)N_NODES * 4;
    int* offs     = (int*)(ws + off);   off += (size_t)(N_NODES + 1) * 4;

    float* out    = (float*)d_out;
    float* aw_out = out + (size_t)N_NODES * 64;

    zero_kernel<<<(2 * N_NODES + 255) / 256, 256, 0, stream>>>(cnt, 2 * N_NODES);
    hist_kernel<<<(N_EDGES + 255) / 256, 256, 0, stream>>>(tgt, cnt);
    scan_kernel<<<1, 1024, 0, stream>>>(cnt, offs);
    scatter_kernel<<<(N_EDGES + 255) / 256, 256, 0, stream>>>(tgt, offs, cursor, sorted);
    edge_mfma_kernel<<<EDGE_BLOCKS, 256, 0, stream>>>(x, src, ea, W1, b1, W2, b2, av,
                                                      msg, scores);
    agg_kernel<<<(N_NODES + 3) / 4, 256, 0, stream>>>(offs, sorted, scores, msg, out, aw_out);
}